// Round 3
// baseline (1294.828 us; speedup 1.0000x reference)
//
#include <hip/hip_runtime.h>
#include <hip/hip_bf16.h>

// Problem constants
#define H_    16
#define NOPE_ 128
#define ROPE_ 64
#define VDIM_ 128
#define LORA_ 512
#define DM_   2048
#define T_    256
#define S_    32768
#define K_    2048
#define TCH_  64          // token chunk

static constexpr float SCALE_ = 0.072168783648703220563643597562744f; // 1/sqrt(192)

// ---------------------------------------------------------------------------
// Generic tiled fp32 GEMM (NN): C[M,N] = A[M,K] @ B[K,N], batched via blockIdx.z
// BM=32, BN=64, BK=32, 256 threads, thread tile 2x4.
// ---------------------------------------------------------------------------
__global__ __launch_bounds__(256) void gemm_nn(
    const float* __restrict__ A, const float* __restrict__ B, float* __restrict__ C,
    int M, int N, int Kd, int lda, int ldb, int ldc,
    long batchA, long batchB, long batchC)
{
    A += (long)blockIdx.z * batchA;
    B += (long)blockIdx.z * batchB;
    C += (long)blockIdx.z * batchC;

    __shared__ float As[32 * 34];
    __shared__ float Bs[32 * 68];

    const int tid = threadIdx.x;
    const int bm = blockIdx.y * 32;
    const int bn = blockIdx.x * 64;
    const int m0 = (tid >> 4) * 2;
    const int n0 = (tid & 15) * 4;

    float acc[2][4] = {};

    for (int kb = 0; kb < Kd; kb += 32) {
        __syncthreads();
        {   // stage A: 32m x 32k -> As[k][m]
            int m = tid >> 5;
            int k = tid & 31;
            #pragma unroll
            for (int p = 0; p < 4; ++p)
                As[k * 34 + m + p * 8] = A[(long)(bm + m + p * 8) * lda + kb + k];
        }
        {   // stage B: 32k x 64n (float4) -> Bs[k][n]
            int k = tid >> 4;
            int n4 = tid & 15;
            #pragma unroll
            for (int p = 0; p < 2; ++p) {
                float4 v = *(const float4*)(B + (long)(kb + k + p * 16) * ldb + bn + n4 * 4);
                float* dst = &Bs[(k + p * 16) * 68 + n4 * 4];
                dst[0] = v.x; dst[1] = v.y; dst[2] = v.z; dst[3] = v.w;
            }
        }
        __syncthreads();
        #pragma unroll
        for (int kk = 0; kk < 32; ++kk) {
            float a0 = As[kk * 34 + m0];
            float a1 = As[kk * 34 + m0 + 1];
            float4 b = *(const float4*)(&Bs[kk * 68 + n0]);
            acc[0][0] = fmaf(a0, b.x, acc[0][0]);
            acc[0][1] = fmaf(a0, b.y, acc[0][1]);
            acc[0][2] = fmaf(a0, b.z, acc[0][2]);
            acc[0][3] = fmaf(a0, b.w, acc[0][3]);
            acc[1][0] = fmaf(a1, b.x, acc[1][0]);
            acc[1][1] = fmaf(a1, b.y, acc[1][1]);
            acc[1][2] = fmaf(a1, b.z, acc[1][2]);
            acc[1][3] = fmaf(a1, b.w, acc[1][3]);
        }
    }
    #pragma unroll
    for (int i = 0; i < 2; ++i) {
        float4 v = make_float4(acc[i][0], acc[i][1], acc[i][2], acc[i][3]);
        *(float4*)(C + (long)(bm + m0 + i) * ldc + bn + n0) = v;
    }
}

// ---------------------------------------------------------------------------
// Generic tiled fp32 GEMM (NT): C[m,n] = sum_k A[m,k] * B[n,k], batched.
// Same tiling as gemm_nn; B staged transposed into LDS.
// ---------------------------------------------------------------------------
__global__ __launch_bounds__(256) void gemm_nt(
    const float* __restrict__ A, const float* __restrict__ B, float* __restrict__ C,
    int M, int N, int Kd, int lda, int ldb, int ldc,
    long batchA, long batchB, long batchC)
{
    A += (long)blockIdx.z * batchA;
    B += (long)blockIdx.z * batchB;
    C += (long)blockIdx.z * batchC;

    __shared__ float As[32 * 34];
    __shared__ float Bs[32 * 68];

    const int tid = threadIdx.x;
    const int bm = blockIdx.y * 32;
    const int bn = blockIdx.x * 64;
    const int m0 = (tid >> 4) * 2;
    const int n0 = (tid & 15) * 4;

    float acc[2][4] = {};

    for (int kb = 0; kb < Kd; kb += 32) {
        __syncthreads();
        {   // stage A: 32m x 32k -> As[k][m]
            int m = tid >> 5;
            int k = tid & 31;
            #pragma unroll
            for (int p = 0; p < 4; ++p)
                As[k * 34 + m + p * 8] = A[(long)(bm + m + p * 8) * lda + kb + k];
        }
        {   // stage B rows (n-major) transposed: Bs[k][n]
            int n = tid & 63;
            int kq = tid >> 6;   // 0..3
            #pragma unroll
            for (int p = 0; p < 2; ++p) {
                int c4 = kq + p * 4;     // k-chunk of 4
                float4 v = *(const float4*)(B + (long)(bn + n) * ldb + kb + c4 * 4);
                Bs[(c4 * 4 + 0) * 68 + n] = v.x;
                Bs[(c4 * 4 + 1) * 68 + n] = v.y;
                Bs[(c4 * 4 + 2) * 68 + n] = v.z;
                Bs[(c4 * 4 + 3) * 68 + n] = v.w;
            }
        }
        __syncthreads();
        #pragma unroll
        for (int kk = 0; kk < 32; ++kk) {
            float a0 = As[kk * 34 + m0];
            float a1 = As[kk * 34 + m0 + 1];
            float4 b = *(const float4*)(&Bs[kk * 68 + n0]);
            acc[0][0] = fmaf(a0, b.x, acc[0][0]);
            acc[0][1] = fmaf(a0, b.y, acc[0][1]);
            acc[0][2] = fmaf(a0, b.z, acc[0][2]);
            acc[0][3] = fmaf(a0, b.w, acc[0][3]);
            acc[1][0] = fmaf(a1, b.x, acc[1][0]);
            acc[1][1] = fmaf(a1, b.y, acc[1][1]);
            acc[1][2] = fmaf(a1, b.z, acc[1][2]);
            acc[1][3] = fmaf(a1, b.w, acc[1][3]);
        }
    }
    #pragma unroll
    for (int i = 0; i < 2; ++i) {
        float4 v = make_float4(acc[i][0], acc[i][1], acc[i][2], acc[i][3]);
        *(float4*)(C + (long)(bm + m0 + i) * ldc + bn + n0) = v;
    }
}

// ---------------------------------------------------------------------------
// RoPE for q_pe: qfull (T,3072) -> qpe (T,H,64). Angles in fp64.
// ---------------------------------------------------------------------------
__global__ __launch_bounds__(256) void rope_q_kernel(
    const float* __restrict__ qfull, const int* __restrict__ pos_q, float* __restrict__ qpe)
{
    int id = blockIdx.x * 256 + threadIdx.x;     // T*H*32 = 131072
    int i = id & 31;
    int h = (id >> 5) & 15;
    int t = id >> 9;
    double inv = exp2(-(double)i * 0.41524101186092026);  // 10000^(-i/32)
    double f = (double)pos_q[t] * inv;
    double fr = f - floor(f * 0.15915494309189535) * 6.283185307179586;
    float sf, cf;
    sincosf((float)fr, &sf, &cf);
    float x1 = qfull[t * 3072 + h * 192 + 128 + i];
    float x2 = qfull[t * 3072 + h * 192 + 160 + i];
    qpe[(t * 16 + h) * 64 + i]      = x1 * cf - x2 * sf;
    qpe[(t * 16 + h) * 64 + 32 + i] = x2 * cf + x1 * sf;
}

// ---------------------------------------------------------------------------
// Scores for one token chunk:
// scores[tl,h,k] = (ql_nope . kv_c[idx] + rope(q_pe) . rope(k_pe[idx])) * SCALE
// k_pe rope computed on the fly (no S-sized scratch).
// ---------------------------------------------------------------------------
__global__ __launch_bounds__(256) void scores_kernel(
    const float* __restrict__ qln,    // chunk: TCH x 16 x 512 (local t)
    const float* __restrict__ qpe,    // full:  T x 16 x 64    (global t)
    const float* __restrict__ kvc,    // S x 512
    const float* __restrict__ kpe,    // S x 64 (raw, un-roped)
    const int*   __restrict__ topk,   // full: T x 2048 (global t)
    float*       __restrict__ scores, // chunk: TCH x 16 x 2048 (local t)
    int t0)
{
    __shared__ float kc[128 * 65];   // 33.3 KB
    __shared__ float qc[16 * 64];    // 4 KB

    const int tl = blockIdx.y;
    const int tg = t0 + tl;
    const int k0 = blockIdx.x * 128;
    const int tid = threadIdx.x;
    const int g = tid & 31;              // compute k-group
    const int h0 = (tid >> 5) * 2;       // compute head pair

    const int* tk = topk + tg * 2048 + k0;

    const int q_h = tid >> 6;            // q stage: 4 rows/pass
    const int q_d = tid & 63;
    const int s_kr = tid >> 4;           // kv stage: 16 rows/pass
    const int s_d4 = tid & 15;

    int idxr[8];
    #pragma unroll
    for (int p = 0; p < 8; ++p) idxr[p] = tk[p * 16 + s_kr];

    float acc[2][4] = {};

    // ---- 8 LORA chunks of 64 dims ----
    for (int c = 0; c < 8; ++c) {
        __syncthreads();
        #pragma unroll
        for (int p = 0; p < 4; ++p) {
            int h = p * 4 + q_h;
            qc[h * 64 + q_d] = qln[(tl * 16 + h) * 512 + c * 64 + q_d];
        }
        #pragma unroll
        for (int p = 0; p < 8; ++p) {
            int k = p * 16 + s_kr;
            float4 v = *(const float4*)(kvc + (long)idxr[p] * 512 + c * 64 + s_d4 * 4);
            float* dst = &kc[k * 65 + s_d4 * 4];
            dst[0] = v.x; dst[1] = v.y; dst[2] = v.z; dst[3] = v.w;
        }
        __syncthreads();
        #pragma unroll 8
        for (int d = 0; d < 64; ++d) {
            float q0 = qc[h0 * 64 + d];
            float q1 = qc[h0 * 64 + 64 + d];
            #pragma unroll
            for (int j = 0; j < 4; ++j) {
                float kv = kc[(g + 32 * j) * 65 + d];
                acc[0][j] = fmaf(q0, kv, acc[0][j]);
                acc[1][j] = fmaf(q1, kv, acc[1][j]);
            }
        }
    }

    // ---- ROPE chunk (64 dims), k_pe roped on the fly ----
    __syncthreads();
    #pragma unroll
    for (int p = 0; p < 4; ++p) {
        int h = p * 4 + q_h;
        qc[h * 64 + q_d] = qpe[(tg * 16 + h) * 64 + q_d];
    }
    {
        const int d0 = s_d4 * 4;
        const float sgn = (d0 < 32) ? -1.f : 1.f;
        double inv[4];
        #pragma unroll
        for (int e = 0; e < 4; ++e)
            inv[e] = exp2(-(double)((d0 + e) & 31) * 0.41524101186092026);
        #pragma unroll 2
        for (int p = 0; p < 8; ++p) {
            int k = p * 16 + s_kr;
            long s = idxr[p];
            float4 v = *(const float4*)(kpe + s * 64 + d0);
            float4 w = *(const float4*)(kpe + s * 64 + (d0 ^ 32));
            const float* vp = &v.x;
            const float* wp = &w.x;
            float* dst = &kc[k * 65 + d0];
            #pragma unroll
            for (int e = 0; e < 4; ++e) {
                double f = (double)s * inv[e];
                double fr = f - floor(f * 0.15915494309189535) * 6.283185307179586;
                float sf, cf;
                sincosf((float)fr, &sf, &cf);
                dst[e] = vp[e] * cf + sgn * wp[e] * sf;
            }
        }
    }
    __syncthreads();
    #pragma unroll 8
    for (int d = 0; d < 64; ++d) {
        float q0 = qc[h0 * 64 + d];
        float q1 = qc[h0 * 64 + 64 + d];
        #pragma unroll
        for (int j = 0; j < 4; ++j) {
            float kv = kc[(g + 32 * j) * 65 + d];
            acc[0][j] = fmaf(q0, kv, acc[0][j]);
            acc[1][j] = fmaf(q1, kv, acc[1][j]);
        }
    }

    #pragma unroll
    for (int i = 0; i < 2; ++i)
        #pragma unroll
        for (int j = 0; j < 4; ++j)
            scores[(long)(tl * 16 + h0 + i) * 2048 + k0 + g + 32 * j] = acc[i][j] * SCALE_;
}

// ---------------------------------------------------------------------------
// Softmax over the k axis, in place. One block per (t,h) row of 2048.
// ---------------------------------------------------------------------------
__global__ __launch_bounds__(256) void softmax_kernel(float* __restrict__ s)
{
    const long row = blockIdx.x;
    float* p = s + row * 2048;
    const int tid = threadIdx.x;
    const int wave = tid >> 6;

    float x[8];
    float mx = -1e30f;
    #pragma unroll
    for (int j = 0; j < 8; ++j) { x[j] = p[tid + 256 * j]; mx = fmaxf(mx, x[j]); }
    #pragma unroll
    for (int o = 32; o > 0; o >>= 1) mx = fmaxf(mx, __shfl_xor(mx, o, 64));

    __shared__ float redm[4];
    __shared__ float reds[4];
    if ((tid & 63) == 0) redm[wave] = mx;
    __syncthreads();
    mx = fmaxf(fmaxf(redm[0], redm[1]), fmaxf(redm[2], redm[3]));

    float sum = 0.f;
    #pragma unroll
    for (int j = 0; j < 8; ++j) { x[j] = __expf(x[j] - mx); sum += x[j]; }
    #pragma unroll
    for (int o = 32; o > 0; o >>= 1) sum += __shfl_xor(sum, o, 64);
    if ((tid & 63) == 0) reds[wave] = sum;
    __syncthreads();
    sum = reds[0] + reds[1] + reds[2] + reds[3];

    float inv = 1.0f / sum;
    #pragma unroll
    for (int j = 0; j < 8; ++j) p[tid + 256 * j] = x[j] * inv;
}

// ---------------------------------------------------------------------------
// o_lat[tl,h,l] = sum_k attn[tl,h,k] * kv_c[idx[tg,k], l]   (one token chunk)
// ---------------------------------------------------------------------------
__global__ __launch_bounds__(256) void olat_kernel(
    const float* __restrict__ attn, const float* __restrict__ kvc,
    const int* __restrict__ topk, float* __restrict__ olat, int t0)
{
    __shared__ float kc2[64 * 132];  // 33.8 KB
    __shared__ float at[16 * 64];    // 4 KB

    const int tl = blockIdx.y;
    const int tg = t0 + tl;
    const int lc = blockIdx.x;           // 0..3
    const int tid = threadIdx.x;
    const int lg = tid & 31;
    const int h0 = (tid >> 5) * 2;

    const int* tk = topk + tg * 2048;

    const int a_h = tid >> 6;
    const int a_k = tid & 63;
    const int s_kr = tid >> 5;           // 8 rows/pass
    const int s_l4 = tid & 31;

    float acc[2][4] = {};

    for (int kt = 0; kt < 2048; kt += 64) {
        __syncthreads();
        #pragma unroll
        for (int p = 0; p < 4; ++p) {
            int h = p * 4 + a_h;
            at[h * 64 + a_k] = attn[(long)(tl * 16 + h) * 2048 + kt + a_k];
        }
        #pragma unroll
        for (int p = 0; p < 8; ++p) {
            int k = p * 8 + s_kr;
            int idx = tk[kt + k];
            float4 v = *(const float4*)(kvc + (long)idx * 512 + lc * 128 + s_l4 * 4);
            *(float4*)(&kc2[k * 132 + s_l4 * 4]) = v;
        }
        __syncthreads();
        #pragma unroll 8
        for (int k = 0; k < 64; ++k) {
            float a0 = at[h0 * 64 + k];
            float a1 = at[h0 * 64 + 64 + k];
            #pragma unroll
            for (int j = 0; j < 4; ++j) {
                float kv = kc2[k * 132 + lg + 32 * j];
                acc[0][j] = fmaf(a0, kv, acc[0][j]);
                acc[1][j] = fmaf(a1, kv, acc[1][j]);
            }
        }
    }
    #pragma unroll
    for (int i = 0; i < 2; ++i)
        #pragma unroll
        for (int j = 0; j < 4; ++j)
            olat[(long)(tl * 16 + h0 + i) * 512 + lc * 128 + lg + 32 * j] = acc[i][j];
}

// ---------------------------------------------------------------------------
// Launch. Workspace footprint: 4,325,376 floats = 16.5 MB.
// ---------------------------------------------------------------------------
extern "C" void kernel_launch(void* const* d_in, const int* in_sizes, int n_in,
                              void* d_out, int out_size, void* d_ws, size_t ws_size,
                              hipStream_t stream)
{
    const float* x    = (const float*)d_in[0];
    const float* Wq   = (const float*)d_in[1];
    const float* W_UK = (const float*)d_in[2];
    const float* W_UV = (const float*)d_in[3];
    const float* Wo   = (const float*)d_in[4];
    const float* kv_c = (const float*)d_in[5];
    const float* k_pe = (const float*)d_in[6];
    const int* topk   = (const int*)d_in[7];
    const int* pos_q  = (const int*)d_in[8];
    float* out        = (float*)d_out;

    // ws layout (floats)
    float* ws = (float*)d_ws;
    float* qfull    = ws;                  // 256*3072          =  786432
    float* qpe      = qfull + 786432;      // 256*16*64         =  262144
    float* qln_c    = qpe + 262144;        // 64*16*512         =  524288
    float* scores_c = qln_c + 524288;      // 64*16*2048        = 2097152
    float* olat_c   = scores_c + 2097152;  // 64*16*512         =  524288
    float* ov_c     = olat_c + 524288;     // 64*2048           =  131072
    const size_t need = (size_t)4325376 * sizeof(float);
    if (ws_size < need) return;  // defensive: fail validation instead of faulting

    // 1) qfull = x @ Wq   (256 x 3072 x 2048)
    gemm_nn<<<dim3(48, 8, 1), 256, 0, stream>>>(x, Wq, qfull,
        256, 3072, 2048, 2048, 3072, 3072, 0, 0, 0);

    // 2) rope q_pe
    rope_q_kernel<<<512, 256, 0, stream>>>(qfull, pos_q, qpe);

    // per-token-chunk pipeline (4 chunks of 64 tokens)
    for (int t0 = 0; t0 < 256; t0 += TCH_) {
        // 3) ql_nope chunk: (64 x 512 x 128) batched over 16 heads
        gemm_nn<<<dim3(8, 2, 16), 256, 0, stream>>>(qfull + (long)t0 * 3072, W_UK, qln_c,
            64, 512, 128, 3072, 512, 8192, 192, 65536, 512);

        // 4) scores chunk (pre-softmax, scaled; k_pe roped on the fly)
        scores_kernel<<<dim3(16, TCH_), 256, 0, stream>>>(
            qln_c, qpe, kv_c, k_pe, topk, scores_c, t0);

        // 5) softmax in place (64*16 rows)
        softmax_kernel<<<1024, 256, 0, stream>>>(scores_c);

        // 6) o_lat chunk
        olat_kernel<<<dim3(4, TCH_), 256, 0, stream>>>(scores_c, kv_c, topk, olat_c, t0);

        // 7) ov chunk: o_lat @ W_UV^T (NT), batched over heads
        gemm_nt<<<dim3(2, 2, 16), 256, 0, stream>>>(olat_c, W_UV, ov_c,
            64, 128, 512, 8192, 512, 2048, 512, 65536, 128);

        // 8) out chunk = ov @ Wo   (64 x 2048 x 2048)
        gemm_nn<<<dim3(32, 2, 1), 256, 0, stream>>>(ov_c, Wo, out + (long)t0 * 2048,
            64, 2048, 2048, 2048, 2048, 2048, 0, 0, 0);
    }
}

// Round 4
// 857.320 us; speedup vs baseline: 1.5103x; 1.5103x over previous
//
#include <hip/hip_runtime.h>
#include <hip/hip_bf16.h>

// Problem constants
#define H_    16
#define NOPE_ 128
#define ROPE_ 64
#define VDIM_ 128
#define LORA_ 512
#define DM_   2048
#define T_    256
#define S_    32768
#define K_    2048

static constexpr float SCALE_ = 0.072168783648703220563643597562744f; // 1/sqrt(192)
static constexpr float LOG2E_ = 1.4426950408889634f;

typedef __attribute__((ext_vector_type(8))) short short8;   // 8 bf16 in 4 VGPRs
typedef __attribute__((ext_vector_type(4))) float f32x4;    // MFMA accumulator

__device__ __forceinline__ ushort f2bf(float f) {
    unsigned u = __float_as_uint(f);
    unsigned r = (u + 0x7FFFu + ((u >> 16) & 1u)) >> 16;    // RNE
    return (ushort)r;
}

// ---------------------------------------------------------------------------
// fp32 GEMM (NN): C[M,N]=A@B, BM=BN=64, BK=16, 256 thr, 4x4 thread tile.
// M%64==0, N%64==0, K%16==0, lda/ldb/ldc and batch offsets multiples of 4.
// ---------------------------------------------------------------------------
__global__ __launch_bounds__(256) void gemm64_nn(
    const float* __restrict__ A, const float* __restrict__ B, float* __restrict__ C,
    int M, int N, int Kd, int lda, int ldb, int ldc,
    long batchA, long batchB, long batchC)
{
    A += (long)blockIdx.z * batchA;
    B += (long)blockIdx.z * batchB;
    C += (long)blockIdx.z * batchC;

    __shared__ float As[16][68];   // [k][m]
    __shared__ float Bs[16][68];   // [k][n]

    const int tid = threadIdx.x;
    const int bm = blockIdx.y * 64;
    const int bn = blockIdx.x * 64;
    const int m_l = tid & 63, kq = tid >> 6;     // A stage
    const int n4 = tid & 15, kr = tid >> 4;      // B stage
    const int cm = (tid >> 4) * 4, cn = (tid & 15) * 4;

    float acc[4][4] = {};

    for (int k0 = 0; k0 < Kd; k0 += 16) {
        __syncthreads();
        {   // A: 64m x 16k
            float4 v = *(const float4*)(A + (long)(bm + m_l) * lda + k0 + kq * 4);
            As[kq * 4 + 0][m_l] = v.x;
            As[kq * 4 + 1][m_l] = v.y;
            As[kq * 4 + 2][m_l] = v.z;
            As[kq * 4 + 3][m_l] = v.w;
        }
        {   // B: 16k x 64n
            float4 v = *(const float4*)(B + (long)(k0 + kr) * ldb + bn + n4 * 4);
            *(float4*)&Bs[kr][n4 * 4] = v;
        }
        __syncthreads();
        #pragma unroll
        for (int kk = 0; kk < 16; ++kk) {
            float4 a = *(const float4*)&As[kk][cm];
            float4 b = *(const float4*)&Bs[kk][cn];
            const float* ap = &a.x;
            const float* bp = &b.x;
            #pragma unroll
            for (int i = 0; i < 4; ++i)
                #pragma unroll
                for (int j = 0; j < 4; ++j)
                    acc[i][j] = fmaf(ap[i], bp[j], acc[i][j]);
        }
    }
    #pragma unroll
    for (int i = 0; i < 4; ++i) {
        float4 v = make_float4(acc[i][0], acc[i][1], acc[i][2], acc[i][3]);
        *(float4*)(C + (long)(bm + cm + i) * ldc + bn + cn) = v;
    }
}

// ---------------------------------------------------------------------------
// GEMM (NT) with bf16 A: C[m,n] = sum_k A[m,k]*B[n,k]. Same tiling.
// ---------------------------------------------------------------------------
__global__ __launch_bounds__(256) void gemm64_nt_a16(
    const ushort* __restrict__ A, const float* __restrict__ B, float* __restrict__ C,
    int M, int N, int Kd, int lda, int ldb, int ldc,
    long batchA, long batchB, long batchC)
{
    A += (long)blockIdx.z * batchA;
    B += (long)blockIdx.z * batchB;
    C += (long)blockIdx.z * batchC;

    __shared__ float As[16][68];
    __shared__ float Bs[16][68];

    const int tid = threadIdx.x;
    const int bm = blockIdx.y * 64;
    const int bn = blockIdx.x * 64;
    const int m_l = tid & 63, kq = tid >> 6;
    const int cm = (tid >> 4) * 4, cn = (tid & 15) * 4;

    float acc[4][4] = {};

    for (int k0 = 0; k0 < Kd; k0 += 16) {
        __syncthreads();
        {   // A (bf16): 64m x 16k
            ushort4 u = *(const ushort4*)(A + (long)(bm + m_l) * lda + k0 + kq * 4);
            As[kq * 4 + 0][m_l] = __uint_as_float((unsigned)u.x << 16);
            As[kq * 4 + 1][m_l] = __uint_as_float((unsigned)u.y << 16);
            As[kq * 4 + 2][m_l] = __uint_as_float((unsigned)u.z << 16);
            As[kq * 4 + 3][m_l] = __uint_as_float((unsigned)u.w << 16);
        }
        {   // B rows (n-major) transposed into [k][n]
            float4 v = *(const float4*)(B + (long)(bn + m_l) * ldb + k0 + kq * 4);
            Bs[kq * 4 + 0][m_l] = v.x;
            Bs[kq * 4 + 1][m_l] = v.y;
            Bs[kq * 4 + 2][m_l] = v.z;
            Bs[kq * 4 + 3][m_l] = v.w;
        }
        __syncthreads();
        #pragma unroll
        for (int kk = 0; kk < 16; ++kk) {
            float4 a = *(const float4*)&As[kk][cm];
            float4 b = *(const float4*)&Bs[kk][cn];
            const float* ap = &a.x;
            const float* bp = &b.x;
            #pragma unroll
            for (int i = 0; i < 4; ++i)
                #pragma unroll
                for (int j = 0; j < 4; ++j)
                    acc[i][j] = fmaf(ap[i], bp[j], acc[i][j]);
        }
    }
    #pragma unroll
    for (int i = 0; i < 4; ++i) {
        float4 v = make_float4(acc[i][0], acc[i][1], acc[i][2], acc[i][3]);
        *(float4*)(C + (long)(bm + cm + i) * ldc + bn + cn) = v;
    }
}

// ---------------------------------------------------------------------------
// qb[:, :, 0:512] = bf16(qln). One float4 per thread.
// ---------------------------------------------------------------------------
__global__ __launch_bounds__(256) void pack_qnope(
    const float* __restrict__ qln, ushort* __restrict__ qb)
{
    int id = blockIdx.x * 256 + threadIdx.x;        // 524288
    int row = id >> 7;                              // 0..4095 (t*16+h)
    int c = (id & 127) * 4;
    float4 v = *(const float4*)(qln + (long)row * 512 + c);
    ushort4 u;
    u.x = f2bf(v.x); u.y = f2bf(v.y); u.z = f2bf(v.z); u.w = f2bf(v.w);
    *(ushort4*)(qb + (long)row * 576 + c) = u;
}

// ---------------------------------------------------------------------------
// qb[:, :, 512:576] = bf16(rope(q_pe)). fp64 angles (validated in R2).
// ---------------------------------------------------------------------------
__global__ __launch_bounds__(256) void pack_qrope(
    const float* __restrict__ qfull, const int* __restrict__ pos_q,
    ushort* __restrict__ qb)
{
    int id = blockIdx.x * 256 + threadIdx.x;     // T*H*32 = 131072
    int i = id & 31;
    int h = (id >> 5) & 15;
    int t = id >> 9;
    double inv = exp2(-(double)i * 0.41524101186092026);  // 10000^(-i/32)
    double f = (double)pos_q[t] * inv;
    double fr = f - floor(f * 0.15915494309189535) * 6.283185307179586;
    float sf, cf;
    sincosf((float)fr, &sf, &cf);
    float x1 = qfull[t * 3072 + h * 192 + 128 + i];
    float x2 = qfull[t * 3072 + h * 192 + 160 + i];
    ushort* q = qb + (long)(t * 16 + h) * 576;
    q[512 + i] = f2bf(x1 * cf - x2 * sf);
    q[544 + i] = f2bf(x2 * cf + x1 * sf);
}

// ---------------------------------------------------------------------------
// Fused flash-MLA attention. One block per token (256 blocks, 4 waves).
// Per 64-key tile: gather kv+rope(k_pe) -> LDS bf16 (once!), S=QK^T via MFMA,
// online softmax (fragment shuffles + LDS cross-wave reduce), O += P.V via
// MFMA reading V columns from the same LDS tile. olat written bf16.
// Layouts (HW-verified): A[m=l&15][k=(l>>4)*8+j]; B[k=(l>>4)*8+j][n=l&15];
// C/D[row=(l>>4)*4+reg][col=l&15].
// ---------------------------------------------------------------------------
#define KBP 584   // kb row pitch in halfs (16B multiple; b128 reads partition banks)

__global__ __launch_bounds__(256, 1) void mla_fused(
    const ushort* __restrict__ qb, const float* __restrict__ kvc,
    const float* __restrict__ kpe, const int* __restrict__ topk,
    ushort* __restrict__ olat)
{
    __shared__ ushort kb[64 * KBP];     // 64 keys x 576 dims bf16 (74.75 KB)
    __shared__ ushort Pl[16 * 72];      // P in [h][key], pitch 72
    __shared__ float wred[2][4][16];    // [max|sum][wave][row]

    const int t = blockIdx.x;
    const int tid = threadIdx.x;
    const int w = tid >> 6;
    const int l = tid & 63;
    const int lm = l & 15;
    const int kq = l >> 4;

    // ---- preload Q A-fragments (18 k-steps of 32) ----
    short8 qa[18];
    {
        const ushort* qrow = qb + (long)(t * 16 + lm) * 576 + kq * 8;
        #pragma unroll
        for (int ks = 0; ks < 18; ++ks)
            qa[ks] = *(const short8*)(qrow + ks * 32);
    }

    // staging roles: 4 threads per key row
    const int skk = tid >> 2;        // key row 0..63
    const int sq = tid & 3;          // quarter
    // rope invariants (dims i0..i0+7 fixed per thread)
    double inv_e[8];
    #pragma unroll
    for (int e = 0; e < 8; ++e)
        inv_e[e] = exp2(-(double)(sq * 8 + e) * 0.41524101186092026);

    const int* tkp = topk + (long)t * 2048;

    f32x4 O[8];
    #pragma unroll
    for (int vt = 0; vt < 8; ++vt) O[vt] = (f32x4){0.f, 0.f, 0.f, 0.f};
    float m_r[4] = {-1e30f, -1e30f, -1e30f, -1e30f};
    float l_r[4] = {0.f, 0.f, 0.f, 0.f};

    for (int kt = 0; kt < 2048; kt += 64) {
        __syncthreads();   // previous tile's LDS reads done
        // ---- stage: gather kv row -> bf16, rope k_pe on the fly ----
        {
            int idx = tkp[kt + skk];
            const float* src = kvc + (long)idx * 512;
            ushort* dst = kb + skk * KBP;
            #pragma unroll
            for (int i = 0; i < 32; ++i) {
                int d = i * 16 + sq * 4;
                float4 v = *(const float4*)(src + d);
                ushort4 u;
                u.x = f2bf(v.x); u.y = f2bf(v.y); u.z = f2bf(v.z); u.w = f2bf(v.w);
                *(ushort4*)(dst + d) = u;
            }
            const float* kp = kpe + (long)idx * 64;
            int i0 = sq * 8;
            float xa[8], xb[8];
            *(float4*)&xa[0] = *(const float4*)(kp + i0);
            *(float4*)&xa[4] = *(const float4*)(kp + i0 + 4);
            *(float4*)&xb[0] = *(const float4*)(kp + i0 + 32);
            *(float4*)&xb[4] = *(const float4*)(kp + i0 + 36);
            #pragma unroll
            for (int e = 0; e < 8; ++e) {
                double f = (double)idx * inv_e[e];
                double fr = f - floor(f * 0.15915494309189535) * 6.283185307179586;
                float sf, cf;
                sincosf((float)fr, &sf, &cf);
                dst[512 + i0 + e] = f2bf(xa[e] * cf - xb[e] * sf);
                dst[544 + i0 + e] = f2bf(xb[e] * cf + xa[e] * sf);
            }
        }
        __syncthreads();

        // ---- S = Q . K^T for this wave's 16 keys ----
        f32x4 S = (f32x4){0.f, 0.f, 0.f, 0.f};
        const int n0 = w * 16;
        {
            const ushort* krow = kb + (n0 + lm) * KBP + kq * 8;
            #pragma unroll
            for (int ks = 0; ks < 18; ++ks) {
                short8 bf = *(const short8*)(krow + ks * 32);
                S = __builtin_amdgcn_mfma_f32_16x16x32_bf16(qa[ks], bf, S, 0, 0, 0);
            }
        }
        float s4[4], mx[4], p[4];
        #pragma unroll
        for (int r = 0; r < 4; ++r) { s4[r] = S[r] * SCALE_; mx[r] = s4[r]; }
        #pragma unroll
        for (int off = 1; off < 16; off <<= 1)
            #pragma unroll
            for (int r = 0; r < 4; ++r)
                mx[r] = fmaxf(mx[r], __shfl_xor(mx[r], off, 64));
        if (lm == 0)
            #pragma unroll
            for (int r = 0; r < 4; ++r) wred[0][w][4 * kq + r] = mx[r];
        __syncthreads();

        float al[4], rs[4];
        #pragma unroll
        for (int r = 0; r < 4; ++r) {
            float tm = fmaxf(fmaxf(wred[0][0][4 * kq + r], wred[0][1][4 * kq + r]),
                             fmaxf(wred[0][2][4 * kq + r], wred[0][3][4 * kq + r]));
            float mn = fmaxf(m_r[r], tm);
            al[r] = exp2f((m_r[r] - mn) * LOG2E_);
            p[r] = exp2f((s4[r] - mn) * LOG2E_);
            m_r[r] = mn;
            rs[r] = p[r];
        }
        #pragma unroll
        for (int off = 1; off < 16; off <<= 1)
            #pragma unroll
            for (int r = 0; r < 4; ++r)
                rs[r] += __shfl_xor(rs[r], off, 64);
        if (lm == 0)
            #pragma unroll
            for (int r = 0; r < 4; ++r) wred[1][w][4 * kq + r] = rs[r];
        #pragma unroll
        for (int r = 0; r < 4; ++r)
            Pl[(4 * kq + r) * 72 + n0 + lm] = f2bf(p[r]);
        // rescale O by alpha
        #pragma unroll
        for (int vt = 0; vt < 8; ++vt)
            #pragma unroll
            for (int r = 0; r < 4; ++r)
                O[vt][r] *= al[r];
        __syncthreads();   // Pl + wred[1] visible

        #pragma unroll
        for (int r = 0; r < 4; ++r) {
            float ts = wred[1][0][4 * kq + r] + wred[1][1][4 * kq + r] +
                       wred[1][2][4 * kq + r] + wred[1][3][4 * kq + r];
            l_r[r] = l_r[r] * al[r] + ts;
        }

        // ---- O += P . V (wave's 128-wide v range) ----
        short8 pa[2];
        #pragma unroll
        for (int ks = 0; ks < 2; ++ks)
            pa[ks] = *(const short8*)(Pl + lm * 72 + ks * 32 + kq * 8);
        const int v0 = w * 128;
        #pragma unroll
        for (int vt = 0; vt < 8; ++vt) {
            const int v = v0 + vt * 16 + lm;
            #pragma unroll
            for (int ks = 0; ks < 2; ++ks) {
                short8 bv;
                #pragma unroll
                for (int j = 0; j < 8; ++j)
                    bv[j] = (short)kb[(ks * 32 + kq * 8 + j) * KBP + v];
                O[vt] = __builtin_amdgcn_mfma_f32_16x16x32_bf16(pa[ks], bv, O[vt], 0, 0, 0);
            }
        }
    }

    // ---- epilogue: normalize + store bf16 ----
    float invl[4];
    #pragma unroll
    for (int r = 0; r < 4; ++r) invl[r] = 1.0f / l_r[r];
    #pragma unroll
    for (int vt = 0; vt < 8; ++vt)
        #pragma unroll
        for (int r = 0; r < 4; ++r)
            olat[(long)(t * 16 + 4 * kq + r) * 512 + w * 128 + vt * 16 + lm] =
                f2bf(O[vt][r] * invl[r]);
}

// ---------------------------------------------------------------------------
// Launch. ws footprint = 16,252,928 bytes (≤ 17,301,504 proven safe in R2).
// ---------------------------------------------------------------------------
extern "C" void kernel_launch(void* const* d_in, const int* in_sizes, int n_in,
                              void* d_out, int out_size, void* d_ws, size_t ws_size,
                              hipStream_t stream)
{
    const float* x    = (const float*)d_in[0];
    const float* Wq   = (const float*)d_in[1];
    const float* W_UK = (const float*)d_in[2];
    const float* W_UV = (const float*)d_in[3];
    const float* Wo   = (const float*)d_in[4];
    const float* kv_c = (const float*)d_in[5];
    const float* k_pe = (const float*)d_in[6];
    const int* topk   = (const int*)d_in[7];
    const int* pos_q  = (const int*)d_in[8];
    float* out        = (float*)d_out;

    char* wsb = (char*)d_ws;
    ushort* qb   = (ushort*)wsb;                          // 256*16*576 bf16 = 4,718,592 B
    float* qfull = (float*)(wsb + 4718592);               // 256*3072 f32   = 3,145,728 B
    float* qln   = (float*)(wsb + 4718592 + 3145728);     // 256*16*512 f32 = 8,388,608 B
    ushort* olat = (ushort*)qln;                          // overlay (4,194,304 B; qln dead)
    float* ov    = qfull;                                 // overlay (2,097,152 B; qfull dead)
    if (ws_size < (size_t)16252928) return;  // defensive: fail validation, don't fault

    // 1) qfull = x @ Wq   (256 x 3072 x 2048)
    gemm64_nn<<<dim3(48, 4, 1), 256, 0, stream>>>(x, Wq, qfull,
        256, 3072, 2048, 2048, 3072, 3072, 0, 0, 0);

    // 2) qln[t,h,:] = q_nope[t,h,:] @ W_UK[h]   (256 x 512 x 128, batched over h)
    gemm64_nn<<<dim3(8, 4, 16), 256, 0, stream>>>(qfull, W_UK, qln,
        256, 512, 128, 3072, 512, 8192, 192, 65536, 512);

    // 3) pack Q bf16: nope part + roped pe part
    pack_qnope<<<2048, 256, 0, stream>>>(qln, qb);
    pack_qrope<<<512, 256, 0, stream>>>(qfull, pos_q, qb);

    // 4) fused attention -> olat (bf16)
    mla_fused<<<256, 256, 0, stream>>>(qb, kv_c, k_pe, topk, olat);

    // 5) ov[t, h*128+v] = olat[t,h,:] . W_UV[h,v,:]   (NT, bf16 A)
    gemm64_nt_a16<<<dim3(2, 4, 16), 256, 0, stream>>>(olat, W_UV, ov,
        256, 128, 512, 8192, 512, 2048, 512, 65536, 128);

    // 6) out = ov @ Wo   (256 x 2048 x 2048)
    gemm64_nn<<<dim3(32, 4, 1), 256, 0, stream>>>(ov, Wo, out,
        256, 2048, 2048, 2048, 2048, 2048, 0, 0, 0);
}

// Round 5
// 597.843 us; speedup vs baseline: 2.1658x; 1.4340x over previous
//
#include <hip/hip_runtime.h>
#include <hip/hip_bf16.h>

// Problem constants
#define H_    16
#define NOPE_ 128
#define ROPE_ 64
#define VDIM_ 128
#define LORA_ 512
#define DM_   2048
#define T_    256
#define S_    32768
#define K_    2048

static constexpr float SCALE_ = 0.072168783648703220563643597562744f; // 1/sqrt(192)
static constexpr float LOG2E_ = 1.4426950408889634f;

typedef __attribute__((ext_vector_type(8))) short short8;   // 8 bf16 in 4 VGPRs
typedef __attribute__((ext_vector_type(4))) float f32x4;    // MFMA accumulator

__device__ __forceinline__ ushort f2bf(float f) {
    unsigned u = __float_as_uint(f);
    unsigned r = (u + 0x7FFFu + ((u >> 16) & 1u)) >> 16;    // RNE
    return (ushort)r;
}
__device__ __forceinline__ float bf2f(ushort u) {
    return __uint_as_float((unsigned)u << 16);
}

// ---------------------------------------------------------------------------
// fp32 GEMM (NN): C[M,N]=A@B, BM=BN=64, BK=16, 256 thr, 4x4 thread tile.
// ---------------------------------------------------------------------------
__global__ __launch_bounds__(256) void gemm64_nn(
    const float* __restrict__ A, const float* __restrict__ B, float* __restrict__ C,
    int M, int N, int Kd, int lda, int ldb, int ldc,
    long batchA, long batchB, long batchC)
{
    A += (long)blockIdx.z * batchA;
    B += (long)blockIdx.z * batchB;
    C += (long)blockIdx.z * batchC;

    __shared__ float As[16][68];   // [k][m]
    __shared__ float Bs[16][68];   // [k][n]

    const int tid = threadIdx.x;
    const int bm = blockIdx.y * 64;
    const int bn = blockIdx.x * 64;
    const int m_l = tid & 63, kq = tid >> 6;     // A stage
    const int n4 = tid & 15, kr = tid >> 4;      // B stage
    const int cm = (tid >> 4) * 4, cn = (tid & 15) * 4;

    float acc[4][4] = {};

    for (int k0 = 0; k0 < Kd; k0 += 16) {
        __syncthreads();
        {   // A: 64m x 16k
            float4 v = *(const float4*)(A + (long)(bm + m_l) * lda + k0 + kq * 4);
            As[kq * 4 + 0][m_l] = v.x;
            As[kq * 4 + 1][m_l] = v.y;
            As[kq * 4 + 2][m_l] = v.z;
            As[kq * 4 + 3][m_l] = v.w;
        }
        {   // B: 16k x 64n
            float4 v = *(const float4*)(B + (long)(k0 + kr) * ldb + bn + n4 * 4);
            *(float4*)&Bs[kr][n4 * 4] = v;
        }
        __syncthreads();
        #pragma unroll
        for (int kk = 0; kk < 16; ++kk) {
            float4 a = *(const float4*)&As[kk][cm];
            float4 b = *(const float4*)&Bs[kk][cn];
            const float* ap = &a.x;
            const float* bp = &b.x;
            #pragma unroll
            for (int i = 0; i < 4; ++i)
                #pragma unroll
                for (int j = 0; j < 4; ++j)
                    acc[i][j] = fmaf(ap[i], bp[j], acc[i][j]);
        }
    }
    #pragma unroll
    for (int i = 0; i < 4; ++i) {
        float4 v = make_float4(acc[i][0], acc[i][1], acc[i][2], acc[i][3]);
        *(float4*)(C + (long)(bm + cm + i) * ldc + bn + cn) = v;
    }
}

// ---------------------------------------------------------------------------
// GEMM (NT) with bf16 A: C[m,n] = sum_k A[m,k]*B[n,k]. Same tiling.
// ---------------------------------------------------------------------------
__global__ __launch_bounds__(256) void gemm64_nt_a16(
    const ushort* __restrict__ A, const float* __restrict__ B, float* __restrict__ C,
    int M, int N, int Kd, int lda, int ldb, int ldc,
    long batchA, long batchB, long batchC)
{
    A += (long)blockIdx.z * batchA;
    B += (long)blockIdx.z * batchB;
    C += (long)blockIdx.z * batchC;

    __shared__ float As[16][68];
    __shared__ float Bs[16][68];

    const int tid = threadIdx.x;
    const int bm = blockIdx.y * 64;
    const int bn = blockIdx.x * 64;
    const int m_l = tid & 63, kq = tid >> 6;
    const int cm = (tid >> 4) * 4, cn = (tid & 15) * 4;

    float acc[4][4] = {};

    for (int k0 = 0; k0 < Kd; k0 += 16) {
        __syncthreads();
        {   // A (bf16): 64m x 16k
            ushort4 u = *(const ushort4*)(A + (long)(bm + m_l) * lda + k0 + kq * 4);
            As[kq * 4 + 0][m_l] = bf2f(u.x);
            As[kq * 4 + 1][m_l] = bf2f(u.y);
            As[kq * 4 + 2][m_l] = bf2f(u.z);
            As[kq * 4 + 3][m_l] = bf2f(u.w);
        }
        {   // B rows (n-major) transposed into [k][n]
            float4 v = *(const float4*)(B + (long)(bn + m_l) * ldb + k0 + kq * 4);
            Bs[kq * 4 + 0][m_l] = v.x;
            Bs[kq * 4 + 1][m_l] = v.y;
            Bs[kq * 4 + 2][m_l] = v.z;
            Bs[kq * 4 + 3][m_l] = v.w;
        }
        __syncthreads();
        #pragma unroll
        for (int kk = 0; kk < 16; ++kk) {
            float4 a = *(const float4*)&As[kk][cm];
            float4 b = *(const float4*)&Bs[kk][cn];
            const float* ap = &a.x;
            const float* bp = &b.x;
            #pragma unroll
            for (int i = 0; i < 4; ++i)
                #pragma unroll
                for (int j = 0; j < 4; ++j)
                    acc[i][j] = fmaf(ap[i], bp[j], acc[i][j]);
        }
    }
    #pragma unroll
    for (int i = 0; i < 4; ++i) {
        float4 v = make_float4(acc[i][0], acc[i][1], acc[i][2], acc[i][3]);
        *(float4*)(C + (long)(bm + cm + i) * ldc + bn + cn) = v;
    }
}

// ---------------------------------------------------------------------------
// qb[:, :, 0:512] = bf16(qln). One float4 per thread.
// ---------------------------------------------------------------------------
__global__ __launch_bounds__(256) void pack_qnope(
    const float* __restrict__ qln, ushort* __restrict__ qb)
{
    int id = blockIdx.x * 256 + threadIdx.x;        // 524288
    int row = id >> 7;                              // 0..4095 (t*16+h)
    int c = (id & 127) * 4;
    float4 v = *(const float4*)(qln + (long)row * 512 + c);
    ushort4 u;
    u.x = f2bf(v.x); u.y = f2bf(v.y); u.z = f2bf(v.z); u.w = f2bf(v.w);
    *(ushort4*)(qb + (long)row * 576 + c) = u;
}

// ---------------------------------------------------------------------------
// qb[:, :, 512:576] = bf16(rope(q_pe)). fp64 angles (validated R2-R4).
// ---------------------------------------------------------------------------
__global__ __launch_bounds__(256) void pack_qrope(
    const float* __restrict__ qfull, const int* __restrict__ pos_q,
    ushort* __restrict__ qb)
{
    int id = blockIdx.x * 256 + threadIdx.x;     // T*H*32 = 131072
    int i = id & 31;
    int h = (id >> 5) & 15;
    int t = id >> 9;
    double inv = exp2(-(double)i * 0.41524101186092026);  // 10000^(-i/32)
    double f = (double)pos_q[t] * inv;
    double fr = f - floor(f * 0.15915494309189535) * 6.283185307179586;
    float sf, cf;
    sincosf((float)fr, &sf, &cf);
    float x1 = qfull[t * 3072 + h * 192 + 128 + i];
    float x2 = qfull[t * 3072 + h * 192 + 160 + i];
    ushort* q = qb + (long)(t * 16 + h) * 576;
    q[512 + i] = f2bf(x1 * cf - x2 * sf);
    q[544 + i] = f2bf(x2 * cf + x1 * sf);
}

// ---------------------------------------------------------------------------
// Precompute kvb[s][0:512]=bf16(kv_c[s]), kvb[s][512:576]=bf16(rope(k_pe[s],s)).
// Makes the gather table bf16 (37.75 MB, L3-resident) and removes cvt+rope
// from the attention hot loop.
// ---------------------------------------------------------------------------
__global__ __launch_bounds__(256) void prep_kvb(
    const float* __restrict__ kvc, const float* __restrict__ kpe,
    ushort* __restrict__ kvb)
{
    int id = blockIdx.x * 256 + threadIdx.x;   // 32768*72 = 2,359,296
    int s = id / 72;
    int c = id - s * 72;
    if (c < 64) {
        const float* src = kvc + (long)s * 512 + c * 8;
        float4 v0 = *(const float4*)src;
        float4 v1 = *(const float4*)(src + 4);
        ushort4 a, b;
        a.x = f2bf(v0.x); a.y = f2bf(v0.y); a.z = f2bf(v0.z); a.w = f2bf(v0.w);
        b.x = f2bf(v1.x); b.y = f2bf(v1.y); b.z = f2bf(v1.z); b.w = f2bf(v1.w);
        ushort* dst = kvb + (long)s * 576 + c * 8;
        *(ushort4*)dst = a;
        *(ushort4*)(dst + 4) = b;
    } else {
        int q = c - 64;                       // 0..7 -> rope dims q*8..q*8+7
        const float* kp = kpe + (long)s * 64;
        ushort* dst = kvb + (long)s * 576 + 512 + q * 8;
        #pragma unroll
        for (int e = 0; e < 8; ++e) {
            int d = q * 8 + e;
            int i = d & 31;
            double inv = exp2(-(double)i * 0.41524101186092026);
            double f = (double)s * inv;
            double fr = f - floor(f * 0.15915494309189535) * 6.283185307179586;
            float sf, cf;
            sincosf((float)fr, &sf, &cf);
            float x1 = kp[i], x2 = kp[32 + i];
            dst[e] = (d < 32) ? f2bf(x1 * cf - x2 * sf) : f2bf(x2 * cf + x1 * sf);
        }
    }
}

// ---------------------------------------------------------------------------
// Fused flash-MLA attention, split-K over 2 blocks/token (512 blocks, 2/CU).
// Each block: 1024 keys = 16 tiles of 64. Emits unnormalized partial O (bf16)
// + (m,l) fp32; combine_kernel merges.
// USE_KVB: gather pre-packed bf16 rows (fast). Else gather fp32 + rope (safe).
// Layouts (HW-verified): A[m=l&15][k=(l>>4)*8+j]; B[k=(l>>4)*8+j][n=l&15];
// C/D[row=(l>>4)*4+reg][col=l&15].
// ---------------------------------------------------------------------------
#define KBP 584   // kb row pitch in halfs (16B multiple)

template<bool USE_KVB>
__global__ __launch_bounds__(256, 1) void mla_fused_split(
    const ushort* __restrict__ qb, const float* __restrict__ kvc,
    const float* __restrict__ kpe, const ushort* __restrict__ kvb,
    const int* __restrict__ topk,
    ushort* __restrict__ Opart, float* __restrict__ ml)
{
    __shared__ ushort kb[64 * KBP];     // 64 keys x 576 dims bf16 (74.75 KB)
    __shared__ ushort Pl[16 * 72];      // P in [h][key]
    __shared__ float wred[2][4][16];    // [max|sum][wave][row]

    const int t = blockIdx.x;
    const int sp = blockIdx.y;          // split 0/1
    const int tid = threadIdx.x;
    const int w = tid >> 6;
    const int l = tid & 63;
    const int lm = l & 15;
    const int kq = l >> 4;

    // ---- preload Q A-fragments (18 k-steps of 32) ----
    short8 qa[18];
    {
        const ushort* qrow = qb + (long)(t * 16 + lm) * 576 + kq * 8;
        #pragma unroll
        for (int ks = 0; ks < 18; ++ks)
            qa[ks] = *(const short8*)(qrow + ks * 32);
    }

    // staging roles: 4 threads per key row
    const int skk = tid >> 2;        // key row 0..63
    const int sq = tid & 3;          // quarter
    double inv_e[8];                 // only used (and kept) in fallback path
    #pragma unroll
    for (int e = 0; e < 8; ++e)
        inv_e[e] = exp2(-(double)(sq * 8 + e) * 0.41524101186092026);

    const int* tkp = topk + (long)t * 2048 + sp * 1024;

    f32x4 O[8];
    #pragma unroll
    for (int vt = 0; vt < 8; ++vt) O[vt] = (f32x4){0.f, 0.f, 0.f, 0.f};
    float m_r[4] = {-1e30f, -1e30f, -1e30f, -1e30f};
    float l_r[4] = {0.f, 0.f, 0.f, 0.f};

    for (int kt = 0; kt < 1024; kt += 64) {
        __syncthreads();   // previous tile's LDS reads done
        // ---- stage tile ----
        {
            int idx = tkp[kt + skk];
            if constexpr (USE_KVB) {
                const ushort* src = kvb + (long)idx * 576;
                ushort* dst = kb + skk * KBP;
                #pragma unroll
                for (int i = 0; i < 18; ++i) {
                    int off = i * 32 + sq * 8;
                    *(uint4*)(dst + off) = *(const uint4*)(src + off);
                }
            } else {
                const float* src = kvc + (long)idx * 512;
                ushort* dst = kb + skk * KBP;
                #pragma unroll
                for (int i = 0; i < 32; ++i) {
                    int d = i * 16 + sq * 4;
                    float4 v = *(const float4*)(src + d);
                    ushort4 u;
                    u.x = f2bf(v.x); u.y = f2bf(v.y); u.z = f2bf(v.z); u.w = f2bf(v.w);
                    *(ushort4*)(dst + d) = u;
                }
                const float* kp = kpe + (long)idx * 64;
                int i0 = sq * 8;
                float xa[8], xb[8];
                *(float4*)&xa[0] = *(const float4*)(kp + i0);
                *(float4*)&xa[4] = *(const float4*)(kp + i0 + 4);
                *(float4*)&xb[0] = *(const float4*)(kp + i0 + 32);
                *(float4*)&xb[4] = *(const float4*)(kp + i0 + 36);
                #pragma unroll
                for (int e = 0; e < 8; ++e) {
                    double f = (double)idx * inv_e[e];
                    double fr = f - floor(f * 0.15915494309189535) * 6.283185307179586;
                    float sf, cf;
                    sincosf((float)fr, &sf, &cf);
                    dst[512 + i0 + e] = f2bf(xa[e] * cf - xb[e] * sf);
                    dst[544 + i0 + e] = f2bf(xb[e] * cf + xa[e] * sf);
                }
            }
        }
        __syncthreads();

        // ---- S = Q . K^T for this wave's 16 keys ----
        f32x4 S = (f32x4){0.f, 0.f, 0.f, 0.f};
        const int n0 = w * 16;
        {
            const ushort* krow = kb + (n0 + lm) * KBP + kq * 8;
            #pragma unroll
            for (int ks = 0; ks < 18; ++ks) {
                short8 bf = *(const short8*)(krow + ks * 32);
                S = __builtin_amdgcn_mfma_f32_16x16x32_bf16(qa[ks], bf, S, 0, 0, 0);
            }
        }
        float s4[4], mx[4], p[4];
        #pragma unroll
        for (int r = 0; r < 4; ++r) { s4[r] = S[r] * SCALE_; mx[r] = s4[r]; }
        #pragma unroll
        for (int off = 1; off < 16; off <<= 1)
            #pragma unroll
            for (int r = 0; r < 4; ++r)
                mx[r] = fmaxf(mx[r], __shfl_xor(mx[r], off, 64));
        if (lm == 0)
            #pragma unroll
            for (int r = 0; r < 4; ++r) wred[0][w][4 * kq + r] = mx[r];
        __syncthreads();

        float al[4], rs[4];
        #pragma unroll
        for (int r = 0; r < 4; ++r) {
            float tm = fmaxf(fmaxf(wred[0][0][4 * kq + r], wred[0][1][4 * kq + r]),
                             fmaxf(wred[0][2][4 * kq + r], wred[0][3][4 * kq + r]));
            float mn = fmaxf(m_r[r], tm);
            al[r] = exp2f((m_r[r] - mn) * LOG2E_);
            p[r] = exp2f((s4[r] - mn) * LOG2E_);
            m_r[r] = mn;
            rs[r] = p[r];
        }
        #pragma unroll
        for (int off = 1; off < 16; off <<= 1)
            #pragma unroll
            for (int r = 0; r < 4; ++r)
                rs[r] += __shfl_xor(rs[r], off, 64);
        if (lm == 0)
            #pragma unroll
            for (int r = 0; r < 4; ++r) wred[1][w][4 * kq + r] = rs[r];
        #pragma unroll
        for (int r = 0; r < 4; ++r)
            Pl[(4 * kq + r) * 72 + n0 + lm] = f2bf(p[r]);
        // rescale O by alpha
        #pragma unroll
        for (int vt = 0; vt < 8; ++vt)
            #pragma unroll
            for (int r = 0; r < 4; ++r)
                O[vt][r] *= al[r];
        __syncthreads();   // Pl + wred[1] visible

        #pragma unroll
        for (int r = 0; r < 4; ++r) {
            float ts = wred[1][0][4 * kq + r] + wred[1][1][4 * kq + r] +
                       wred[1][2][4 * kq + r] + wred[1][3][4 * kq + r];
            l_r[r] = l_r[r] * al[r] + ts;
        }

        // ---- O += P . V (wave's 128-wide v range) ----
        short8 pa[2];
        #pragma unroll
        for (int ks = 0; ks < 2; ++ks)
            pa[ks] = *(const short8*)(Pl + lm * 72 + ks * 32 + kq * 8);
        const int v0 = w * 128;
        #pragma unroll
        for (int vt = 0; vt < 8; ++vt) {
            const int v = v0 + vt * 16 + lm;
            #pragma unroll
            for (int ks = 0; ks < 2; ++ks) {
                short8 bv;
                #pragma unroll
                for (int j = 0; j < 8; ++j)
                    bv[j] = (short)kb[(ks * 32 + kq * 8 + j) * KBP + v];
                O[vt] = __builtin_amdgcn_mfma_f32_16x16x32_bf16(pa[ks], bv, O[vt], 0, 0, 0);
            }
        }
    }

    // ---- epilogue: store unnormalized partial O (bf16) + (m,l) ----
    const long rbase = ((long)sp * 256 + t) * 16;
    #pragma unroll
    for (int vt = 0; vt < 8; ++vt)
        #pragma unroll
        for (int r = 0; r < 4; ++r)
            Opart[(rbase + 4 * kq + r) * 512 + w * 128 + vt * 16 + lm] = f2bf(O[vt][r]);
    if (w == 0 && lm == 0) {
        #pragma unroll
        for (int r = 0; r < 4; ++r) {
            ml[(rbase + 4 * kq + r) * 2 + 0] = m_r[r];
            ml[(rbase + 4 * kq + r) * 2 + 1] = l_r[r];
        }
    }
}

// ---------------------------------------------------------------------------
// Merge the 2 split-K partials -> olat bf16.
// ---------------------------------------------------------------------------
__global__ __launch_bounds__(256) void combine_kernel(
    const ushort* __restrict__ Opart, const float* __restrict__ ml,
    ushort* __restrict__ olat)
{
    const int t = blockIdx.x;
    const int h = threadIdx.x >> 4;
    const int v0 = (threadIdx.x & 15) * 32;
    const long r0 = (long)t * 16 + h;
    const long r1 = (long)(256 + t) * 16 + h;
    float m0 = ml[r0 * 2], l0 = ml[r0 * 2 + 1];
    float m1 = ml[r1 * 2], l1 = ml[r1 * 2 + 1];
    float M = fmaxf(m0, m1);
    float w0 = exp2f((m0 - M) * LOG2E_);
    float w1 = exp2f((m1 - M) * LOG2E_);
    float inv = 1.0f / (w0 * l0 + w1 * l1);
    const ushort* p0 = Opart + r0 * 512 + v0;
    const ushort* p1 = Opart + r1 * 512 + v0;
    ushort* po = olat + r0 * 512 + v0;
    #pragma unroll
    for (int i = 0; i < 32; i += 4) {
        ushort4 a = *(const ushort4*)(p0 + i);
        ushort4 b = *(const ushort4*)(p1 + i);
        ushort4 o;
        o.x = f2bf((w0 * bf2f(a.x) + w1 * bf2f(b.x)) * inv);
        o.y = f2bf((w0 * bf2f(a.y) + w1 * bf2f(b.y)) * inv);
        o.z = f2bf((w0 * bf2f(a.z) + w1 * bf2f(b.z)) * inv);
        o.w = f2bf((w0 * bf2f(a.w) + w1 * bf2f(b.w)) * inv);
        *(ushort4*)(po + i) = o;
    }
}

// ---------------------------------------------------------------------------
// Launch. Base footprint 16,252,928 B (proven safe); fast path additionally
// needs kvb (37,748,736 B) => 54,001,664 B, used only if ws_size allows.
// ---------------------------------------------------------------------------
extern "C" void kernel_launch(void* const* d_in, const int* in_sizes, int n_in,
                              void* d_out, int out_size, void* d_ws, size_t ws_size,
                              hipStream_t stream)
{
    const float* x    = (const float*)d_in[0];
    const float* Wq   = (const float*)d_in[1];
    const float* W_UK = (const float*)d_in[2];
    const float* W_UV = (const float*)d_in[3];
    const float* Wo   = (const float*)d_in[4];
    const float* kv_c = (const float*)d_in[5];
    const float* k_pe = (const float*)d_in[6];
    const int* topk   = (const int*)d_in[7];
    const int* pos_q  = (const int*)d_in[8];
    float* out        = (float*)d_out;

    char* wsb = (char*)d_ws;
    ushort* qb    = (ushort*)wsb;                      // 4,718,592 B
    float*  qfull = (float*)(wsb + 4718592);           // 3,145,728 B
    float*  ov    = qfull;                             // overlay [0, 2,097,152)
    float*  ml    = (float*)(wsb + 4718592 + 2097152); // 131,072 B (qfull tail; qfull dead)
    float*  qln   = (float*)(wsb + 7864320);           // 8,388,608 B
    ushort* Opart = (ushort*)qln;                      // overlay (qln dead after pack)
    ushort* olat  = qb;                                // overlay (qb dead after attention)
    ushort* kvb   = (ushort*)(wsb + 16252928);         // 37,748,736 B (fast path)
    if (ws_size < (size_t)16252928) return;            // fail validation, don't fault
    const bool fast = ws_size >= (size_t)54001664;

    // 0) prep bf16 kv table (fast path only)
    if (fast)
        prep_kvb<<<9216, 256, 0, stream>>>(kv_c, k_pe, kvb);

    // 1) qfull = x @ Wq   (256 x 3072 x 2048)
    gemm64_nn<<<dim3(48, 4, 1), 256, 0, stream>>>(x, Wq, qfull,
        256, 3072, 2048, 2048, 3072, 3072, 0, 0, 0);

    // 2) qln[t,h,:] = q_nope[t,h,:] @ W_UK[h]   (256 x 512 x 128, batched over h)
    gemm64_nn<<<dim3(8, 4, 16), 256, 0, stream>>>(qfull, W_UK, qln,
        256, 512, 128, 3072, 512, 8192, 192, 65536, 512);

    // 3) pack Q bf16: nope part + roped pe part
    pack_qnope<<<2048, 256, 0, stream>>>(qln, qb);
    pack_qrope<<<512, 256, 0, stream>>>(qfull, pos_q, qb);

    // 4) fused attention, split-K=2 -> partials
    if (fast)
        mla_fused_split<true><<<dim3(256, 2), 256, 0, stream>>>(
            qb, kv_c, k_pe, kvb, topk, Opart, ml);
    else
        mla_fused_split<false><<<dim3(256, 2), 256, 0, stream>>>(
            qb, kv_c, k_pe, kvb, topk, Opart, ml);

    // 5) combine partials -> olat (bf16, overlays qb)
    combine_kernel<<<256, 256, 0, stream>>>(Opart, ml, olat);

    // 6) ov[t, h*128+v] = olat[t,h,:] . W_UV[h,v,:]   (NT, bf16 A)
    gemm64_nt_a16<<<dim3(2, 4, 16), 256, 0, stream>>>(olat, W_UV, ov,
        256, 128, 512, 8192, 512, 2048, 512, 65536, 128);

    // 7) out = ov @ Wo   (256 x 2048 x 2048)
    gemm64_nn<<<dim3(32, 4, 1), 256, 0, stream>>>(ov, Wo, out,
        256, 2048, 2048, 2048, 2048, 2048, 0, 0, 0);
}

// Round 6
// 435.686 us; speedup vs baseline: 2.9719x; 1.3722x over previous
//
#include <hip/hip_runtime.h>
#include <hip/hip_bf16.h>

// Problem constants
#define H_    16
#define NOPE_ 128
#define ROPE_ 64
#define VDIM_ 128
#define LORA_ 512
#define DM_   2048
#define T_    256
#define S_    32768
#define K_    2048

static constexpr float SCALE_ = 0.072168783648703220563643597562744f; // 1/sqrt(192)
static constexpr float LOG2E_ = 1.4426950408889634f;

typedef __attribute__((ext_vector_type(8))) short short8;   // 8 bf16 in 4 VGPRs
typedef __attribute__((ext_vector_type(4))) float f32x4;    // MFMA accumulator

__device__ __forceinline__ ushort f2bf(float f) {
    unsigned u = __float_as_uint(f);
    unsigned r = (u + 0x7FFFu + ((u >> 16) & 1u)) >> 16;    // RNE
    return (ushort)r;
}
__device__ __forceinline__ float bf2f(ushort u) {
    return __uint_as_float((unsigned)u << 16);
}

// ---------------------------------------------------------------------------
// bf16 MFMA GEMM: C[M,N] = A[M,K] @ B[K,N] (B_NT: B is [N][K] n-major).
// BM=BN=64, BK=64, 256 thr (4 waves, each a 32x32 quadrant, 2x2 MFMA tiles).
// A fp32 or bf16 (A_BF16); B fp32; C fp32 or bf16 (C_BF16).
// LDS: As [m][k] bf16 pitch 72 (b128 frag reads, 2-way conflict = free);
//      Bs NT: [n][k] pitch 72 (b128 reads); NN: [k][n] pitch 68 (u16 reads).
// Layouts (HW-verified in attention): A[m=l&15][k=(l>>4)*8+j];
// B[k=(l>>4)*8+j][n=l&15]; C/D[row=(l>>4)*4+reg][col=l&15].
// Requires M%64==0, N%64==0, K%64==0.
// ---------------------------------------------------------------------------
template<bool A_BF16, bool B_NT, bool C_BF16>
__global__ __launch_bounds__(256) void gemm_mfma(
    const void* __restrict__ Av, const float* __restrict__ B, void* __restrict__ Cv,
    int M, int N, int Kd, int lda, int ldb, int ldc,
    long batchA, long batchB, long batchC)
{
    __shared__ ushort As[64 * 72];
    __shared__ ushort Bs[64 * 72];

    const int tid = threadIdx.x;
    const int w  = tid >> 6;
    const int l  = tid & 63;
    const int lm = l & 15;
    const int kq = l >> 4;
    const int bm = blockIdx.y * 64;
    const int bn = blockIdx.x * 64;
    const int m0 = (w >> 1) * 32;
    const int n0 = (w & 1) * 32;

    const float*  Af = A_BF16 ? nullptr : ((const float*)Av)  + (long)blockIdx.z * batchA;
    const ushort* Ah = A_BF16 ? ((const ushort*)Av) + (long)blockIdx.z * batchA : nullptr;
    B += (long)blockIdx.z * batchB;

    f32x4 acc[2][2];
    #pragma unroll
    for (int i = 0; i < 2; ++i)
        #pragma unroll
        for (int j = 0; j < 2; ++j) acc[i][j] = (f32x4){0.f, 0.f, 0.f, 0.f};

    for (int k0 = 0; k0 < Kd; k0 += 64) {
        __syncthreads();
        // ---- stage A -> As[m][k] bf16 ----
        if constexpr (A_BF16) {
            int m = tid >> 2, ko = (tid & 3) * 16;
            const ushort* src = Ah + (long)(bm + m) * lda + k0 + ko;
            *(uint4*)(As + m * 72 + ko)     = *(const uint4*)(src);
            *(uint4*)(As + m * 72 + ko + 8) = *(const uint4*)(src + 8);
        } else {
            int mr = tid >> 4, kk = (tid & 15) * 4;
            #pragma unroll
            for (int p = 0; p < 4; ++p) {
                int m = mr + p * 16;
                float4 v = *(const float4*)(Af + (long)(bm + m) * lda + k0 + kk);
                ushort4 u;
                u.x = f2bf(v.x); u.y = f2bf(v.y); u.z = f2bf(v.z); u.w = f2bf(v.w);
                *(ushort4*)(As + m * 72 + kk) = u;
            }
        }
        // ---- stage B ----
        if constexpr (B_NT) {
            // rows n-major, contiguous k -> Bs[n][k] pitch 72
            int nr = tid >> 4, kk = (tid & 15) * 4;
            #pragma unroll
            for (int p = 0; p < 4; ++p) {
                int n = nr + p * 16;
                float4 v = *(const float4*)(B + (long)(bn + n) * ldb + k0 + kk);
                ushort4 u;
                u.x = f2bf(v.x); u.y = f2bf(v.y); u.z = f2bf(v.z); u.w = f2bf(v.w);
                *(ushort4*)(Bs + n * 72 + kk) = u;
            }
        } else {
            // row-major [k][n] -> Bs[k][n] pitch 68
            int k = tid >> 2, nq = (tid & 3) * 16;
            #pragma unroll
            for (int p = 0; p < 4; ++p) {
                float4 v = *(const float4*)(B + (long)(k0 + k) * ldb + bn + nq + p * 4);
                ushort4 u;
                u.x = f2bf(v.x); u.y = f2bf(v.y); u.z = f2bf(v.z); u.w = f2bf(v.w);
                *(ushort4*)(Bs + k * 68 + nq + p * 4) = u;
            }
        }
        __syncthreads();
        // ---- compute: 2 k-steps of 32 ----
        #pragma unroll
        for (int ks = 0; ks < 2; ++ks) {
            short8 a[2], b[2];
            #pragma unroll
            for (int mt = 0; mt < 2; ++mt)
                a[mt] = *(const short8*)(As + (m0 + mt * 16 + lm) * 72 + ks * 32 + kq * 8);
            if constexpr (B_NT) {
                #pragma unroll
                for (int nt = 0; nt < 2; ++nt)
                    b[nt] = *(const short8*)(Bs + (n0 + nt * 16 + lm) * 72 + ks * 32 + kq * 8);
            } else {
                #pragma unroll
                for (int nt = 0; nt < 2; ++nt)
                    #pragma unroll
                    for (int j = 0; j < 8; ++j)
                        b[nt][j] = (short)Bs[(ks * 32 + kq * 8 + j) * 68 + n0 + nt * 16 + lm];
            }
            #pragma unroll
            for (int mt = 0; mt < 2; ++mt)
                #pragma unroll
                for (int nt = 0; nt < 2; ++nt)
                    acc[mt][nt] = __builtin_amdgcn_mfma_f32_16x16x32_bf16(
                        a[mt], b[nt], acc[mt][nt], 0, 0, 0);
        }
    }
    // ---- epilogue ----
    #pragma unroll
    for (int mt = 0; mt < 2; ++mt)
        #pragma unroll
        for (int nt = 0; nt < 2; ++nt)
            #pragma unroll
            for (int r = 0; r < 4; ++r) {
                long row = bm + m0 + mt * 16 + kq * 4 + r;
                long col = bn + n0 + nt * 16 + lm;
                if constexpr (C_BF16)
                    ((ushort*)Cv)[(long)blockIdx.z * batchC + row * ldc + col] =
                        f2bf(acc[mt][nt][r]);
                else
                    ((float*)Cv)[(long)blockIdx.z * batchC + row * ldc + col] =
                        acc[mt][nt][r];
            }
}

// ---------------------------------------------------------------------------
// qb[:, :, 512:576] = bf16(rope(q_pe)) from fp32 qfull. fp64 angles.
// ---------------------------------------------------------------------------
__global__ __launch_bounds__(256) void pack_qrope(
    const float* __restrict__ qfull, const int* __restrict__ pos_q,
    ushort* __restrict__ qb)
{
    int id = blockIdx.x * 256 + threadIdx.x;     // T*H*32 = 131072
    int i = id & 31;
    int h = (id >> 5) & 15;
    int t = id >> 9;
    double inv = exp2(-(double)i * 0.41524101186092026);  // 10000^(-i/32)
    double f = (double)pos_q[t] * inv;
    double fr = f - floor(f * 0.15915494309189535) * 6.283185307179586;
    float sf, cf;
    sincosf((float)fr, &sf, &cf);
    float x1 = qfull[t * 3072 + h * 192 + 128 + i];
    float x2 = qfull[t * 3072 + h * 192 + 160 + i];
    ushort* q = qb + (long)(t * 16 + h) * 576;
    q[512 + i] = f2bf(x1 * cf - x2 * sf);
    q[544 + i] = f2bf(x2 * cf + x1 * sf);
}

// ---------------------------------------------------------------------------
// Precompute kvb[s][0:512]=bf16(kv_c[s]), kvb[s][512:576]=bf16(rope(k_pe[s],s)).
// ---------------------------------------------------------------------------
__global__ __launch_bounds__(256) void prep_kvb(
    const float* __restrict__ kvc, const float* __restrict__ kpe,
    ushort* __restrict__ kvb)
{
    int id = blockIdx.x * 256 + threadIdx.x;   // 32768*72 = 2,359,296
    int s = id / 72;
    int c = id - s * 72;
    if (c < 64) {
        const float* src = kvc + (long)s * 512 + c * 8;
        float4 v0 = *(const float4*)src;
        float4 v1 = *(const float4*)(src + 4);
        ushort4 a, b;
        a.x = f2bf(v0.x); a.y = f2bf(v0.y); a.z = f2bf(v0.z); a.w = f2bf(v0.w);
        b.x = f2bf(v1.x); b.y = f2bf(v1.y); b.z = f2bf(v1.z); b.w = f2bf(v1.w);
        ushort* dst = kvb + (long)s * 576 + c * 8;
        *(ushort4*)dst = a;
        *(ushort4*)(dst + 4) = b;
    } else {
        int q = c - 64;                       // 0..7 -> rope dims q*8..q*8+7
        const float* kp = kpe + (long)s * 64;
        ushort* dst = kvb + (long)s * 576 + 512 + q * 8;
        #pragma unroll
        for (int e = 0; e < 8; ++e) {
            int d = q * 8 + e;
            int i = d & 31;
            double inv = exp2(-(double)i * 0.41524101186092026);
            double f = (double)s * inv;
            double fr = f - floor(f * 0.15915494309189535) * 6.283185307179586;
            float sf, cf;
            sincosf((float)fr, &sf, &cf);
            float x1 = kp[i], x2 = kp[32 + i];
            dst[e] = (d < 32) ? f2bf(x1 * cf - x2 * sf) : f2bf(x2 * cf + x1 * sf);
        }
    }
}

// ---------------------------------------------------------------------------
// Fused flash-MLA attention, split-K=2 (512 blocks, 2/CU). Gathers pre-packed
// bf16 kvb rows. Emits unnormalized partial O (bf16) + (m,l) fp32.
// ---------------------------------------------------------------------------
#define KBP 584   // kb row pitch in halfs (16B multiple)

__global__ __launch_bounds__(256, 1) void mla_fused_split(
    const ushort* __restrict__ qb, const ushort* __restrict__ kvb,
    const int* __restrict__ topk,
    ushort* __restrict__ Opart, float* __restrict__ ml)
{
    __shared__ ushort kb[64 * KBP];     // 64 keys x 576 dims bf16 (74.75 KB)
    __shared__ ushort Pl[16 * 72];      // P in [h][key]
    __shared__ float wred[2][4][16];    // [max|sum][wave][row]

    const int t = blockIdx.x;
    const int sp = blockIdx.y;          // split 0/1
    const int tid = threadIdx.x;
    const int w = tid >> 6;
    const int l = tid & 63;
    const int lm = l & 15;
    const int kq = l >> 4;

    // ---- preload Q A-fragments (18 k-steps of 32) ----
    short8 qa[18];
    {
        const ushort* qrow = qb + (long)(t * 16 + lm) * 576 + kq * 8;
        #pragma unroll
        for (int ks = 0; ks < 18; ++ks)
            qa[ks] = *(const short8*)(qrow + ks * 32);
    }

    const int skk = tid >> 2;        // staging: key row 0..63
    const int sq = tid & 3;          // quarter
    const int* tkp = topk + (long)t * 2048 + sp * 1024;

    f32x4 O[8];
    #pragma unroll
    for (int vt = 0; vt < 8; ++vt) O[vt] = (f32x4){0.f, 0.f, 0.f, 0.f};
    float m_r[4] = {-1e30f, -1e30f, -1e30f, -1e30f};
    float l_r[4] = {0.f, 0.f, 0.f, 0.f};

    for (int kt = 0; kt < 1024; kt += 64) {
        __syncthreads();
        {   // gather pre-packed bf16 row
            int idx = tkp[kt + skk];
            const ushort* src = kvb + (long)idx * 576;
            ushort* dst = kb + skk * KBP;
            #pragma unroll
            for (int i = 0; i < 18; ++i) {
                int off = i * 32 + sq * 8;
                *(uint4*)(dst + off) = *(const uint4*)(src + off);
            }
        }
        __syncthreads();

        // ---- S = Q . K^T for this wave's 16 keys ----
        f32x4 S = (f32x4){0.f, 0.f, 0.f, 0.f};
        const int n0 = w * 16;
        {
            const ushort* krow = kb + (n0 + lm) * KBP + kq * 8;
            #pragma unroll
            for (int ks = 0; ks < 18; ++ks) {
                short8 bf = *(const short8*)(krow + ks * 32);
                S = __builtin_amdgcn_mfma_f32_16x16x32_bf16(qa[ks], bf, S, 0, 0, 0);
            }
        }
        float s4[4], mx[4], p[4];
        #pragma unroll
        for (int r = 0; r < 4; ++r) { s4[r] = S[r] * SCALE_; mx[r] = s4[r]; }
        #pragma unroll
        for (int off = 1; off < 16; off <<= 1)
            #pragma unroll
            for (int r = 0; r < 4; ++r)
                mx[r] = fmaxf(mx[r], __shfl_xor(mx[r], off, 64));
        if (lm == 0)
            #pragma unroll
            for (int r = 0; r < 4; ++r) wred[0][w][4 * kq + r] = mx[r];
        __syncthreads();

        float al[4], rs[4];
        #pragma unroll
        for (int r = 0; r < 4; ++r) {
            float tm = fmaxf(fmaxf(wred[0][0][4 * kq + r], wred[0][1][4 * kq + r]),
                             fmaxf(wred[0][2][4 * kq + r], wred[0][3][4 * kq + r]));
            float mn = fmaxf(m_r[r], tm);
            al[r] = exp2f((m_r[r] - mn) * LOG2E_);
            p[r] = exp2f((s4[r] - mn) * LOG2E_);
            m_r[r] = mn;
            rs[r] = p[r];
        }
        #pragma unroll
        for (int off = 1; off < 16; off <<= 1)
            #pragma unroll
            for (int r = 0; r < 4; ++r)
                rs[r] += __shfl_xor(rs[r], off, 64);
        if (lm == 0)
            #pragma unroll
            for (int r = 0; r < 4; ++r) wred[1][w][4 * kq + r] = rs[r];
        #pragma unroll
        for (int r = 0; r < 4; ++r)
            Pl[(4 * kq + r) * 72 + n0 + lm] = f2bf(p[r]);
        #pragma unroll
        for (int vt = 0; vt < 8; ++vt)
            #pragma unroll
            for (int r = 0; r < 4; ++r)
                O[vt][r] *= al[r];
        __syncthreads();   // Pl + wred[1] visible

        #pragma unroll
        for (int r = 0; r < 4; ++r) {
            float ts = wred[1][0][4 * kq + r] + wred[1][1][4 * kq + r] +
                       wred[1][2][4 * kq + r] + wred[1][3][4 * kq + r];
            l_r[r] = l_r[r] * al[r] + ts;
        }

        // ---- O += P . V (wave's 128-wide v range) ----
        short8 pa[2];
        #pragma unroll
        for (int ks = 0; ks < 2; ++ks)
            pa[ks] = *(const short8*)(Pl + lm * 72 + ks * 32 + kq * 8);
        const int v0 = w * 128;
        #pragma unroll
        for (int vt = 0; vt < 8; ++vt) {
            const int v = v0 + vt * 16 + lm;
            #pragma unroll
            for (int ks = 0; ks < 2; ++ks) {
                short8 bv;
                #pragma unroll
                for (int j = 0; j < 8; ++j)
                    bv[j] = (short)kb[(ks * 32 + kq * 8 + j) * KBP + v];
                O[vt] = __builtin_amdgcn_mfma_f32_16x16x32_bf16(pa[ks], bv, O[vt], 0, 0, 0);
            }
        }
    }

    // ---- epilogue: store unnormalized partial O (bf16) + (m,l) ----
    const long rbase = ((long)sp * 256 + t) * 16;
    #pragma unroll
    for (int vt = 0; vt < 8; ++vt)
        #pragma unroll
        for (int r = 0; r < 4; ++r)
            Opart[(rbase + 4 * kq + r) * 512 + w * 128 + vt * 16 + lm] = f2bf(O[vt][r]);
    if (w == 0 && lm == 0) {
        #pragma unroll
        for (int r = 0; r < 4; ++r) {
            ml[(rbase + 4 * kq + r) * 2 + 0] = m_r[r];
            ml[(rbase + 4 * kq + r) * 2 + 1] = l_r[r];
        }
    }
}

// ---------------------------------------------------------------------------
// Merge the 2 split-K partials -> olat bf16.
// ---------------------------------------------------------------------------
__global__ __launch_bounds__(256) void combine_kernel(
    const ushort* __restrict__ Opart, const float* __restrict__ ml,
    ushort* __restrict__ olat)
{
    const int t = blockIdx.x;
    const int h = threadIdx.x >> 4;
    const int v0 = (threadIdx.x & 15) * 32;
    const long r0 = (long)t * 16 + h;
    const long r1 = (long)(256 + t) * 16 + h;
    float m0 = ml[r0 * 2], l0 = ml[r0 * 2 + 1];
    float m1 = ml[r1 * 2], l1 = ml[r1 * 2 + 1];
    float M = fmaxf(m0, m1);
    float w0 = exp2f((m0 - M) * LOG2E_);
    float w1 = exp2f((m1 - M) * LOG2E_);
    float inv = 1.0f / (w0 * l0 + w1 * l1);
    const ushort* p0 = Opart + r0 * 512 + v0;
    const ushort* p1 = Opart + r1 * 512 + v0;
    ushort* po = olat + r0 * 512 + v0;
    #pragma unroll
    for (int i = 0; i < 32; i += 4) {
        ushort4 a = *(const ushort4*)(p0 + i);
        ushort4 b = *(const ushort4*)(p1 + i);
        ushort4 o;
        o.x = f2bf((w0 * bf2f(a.x) + w1 * bf2f(b.x)) * inv);
        o.y = f2bf((w0 * bf2f(a.y) + w1 * bf2f(b.y)) * inv);
        o.z = f2bf((w0 * bf2f(a.z) + w1 * bf2f(b.z)) * inv);
        o.w = f2bf((w0 * bf2f(a.w) + w1 * bf2f(b.w)) * inv);
        *(ushort4*)(po + i) = o;
    }
}

// ---------------------------------------------------------------------------
// Launch. ws footprint exactly 54,001,664 B (proven safe in R5).
// Layout (bytes):
//   qb    [0,          4,718,592)   bf16 q per head, 576/row
//   qfull [4,718,592,  7,864,320)   fp32 (dead after GEMM2+pack_qrope)
//   Opart [4,718,592, 13,107,200)   overlay (written in attention)
//   ov_b  [13,107,200, 14,155,776)  bf16
//   ml    [14,155,776, 14,221,312)
//   kvb   [16,252,928, 54,001,664)  bf16 kv table (unchanged address)
//   olat = overlay of qb [0, 4,194,304) (qb dead after attention)
// ---------------------------------------------------------------------------
extern "C" void kernel_launch(void* const* d_in, const int* in_sizes, int n_in,
                              void* d_out, int out_size, void* d_ws, size_t ws_size,
                              hipStream_t stream)
{
    const float* x    = (const float*)d_in[0];
    const float* Wq   = (const float*)d_in[1];
    const float* W_UK = (const float*)d_in[2];
    const float* W_UV = (const float*)d_in[3];
    const float* Wo   = (const float*)d_in[4];
    const float* kv_c = (const float*)d_in[5];
    const float* k_pe = (const float*)d_in[6];
    const int* topk   = (const int*)d_in[7];
    const int* pos_q  = (const int*)d_in[8];
    float* out        = (float*)d_out;

    char* wsb = (char*)d_ws;
    ushort* qb    = (ushort*)wsb;
    float*  qfull = (float*)(wsb + 4718592);
    ushort* Opart = (ushort*)(wsb + 4718592);          // overlay of qfull
    ushort* ov_b  = (ushort*)(wsb + 13107200);
    float*  ml    = (float*)(wsb + 14155776);
    ushort* olat  = qb;                                // overlay (qb dead)
    ushort* kvb   = (ushort*)(wsb + 16252928);
    if (ws_size < (size_t)54001664) return;            // fail loud, don't fault

    // 0) prep bf16 kv table
    prep_kvb<<<9216, 256, 0, stream>>>(kv_c, k_pe, kvb);

    // 1) qfull = x @ Wq   (256 x 3072 x 2048), fp32 out
    gemm_mfma<false, false, false><<<dim3(48, 4), 256, 0, stream>>>(
        x, Wq, qfull, 256, 3072, 2048, 2048, 3072, 3072, 0, 0, 0);

    // 2) qb[:, :, 0:512] = qnope @ W_UK[h]  (256 x 512 x 128, batched over h)
    //    C row m=t -> qb[(t*16+h)*576 + n]: ldc = 16*576, base offset h*576
    gemm_mfma<false, false, true><<<dim3(8, 4, 16), 256, 0, stream>>>(
        qfull, W_UK, qb, 256, 512, 128, 3072, 512, 9216, 192, 65536, 576);

    // 3) qb[:, :, 512:576] = bf16(rope(q_pe))
    pack_qrope<<<512, 256, 0, stream>>>(qfull, pos_q, qb);

    // 4) fused attention, split-K=2 -> partials
    mla_fused_split<<<dim3(256, 2), 256, 0, stream>>>(qb, kvb, topk, Opart, ml);

    // 5) combine partials -> olat (bf16, overlays qb)
    combine_kernel<<<256, 256, 0, stream>>>(Opart, ml, olat);

    // 6) ov_b[t, h*128+v] = olat[t,h,:] . W_UV[h,v,:]  (NT, A bf16, C bf16)
    gemm_mfma<true, true, true><<<dim3(2, 4, 16), 256, 0, stream>>>(
        olat, W_UV, ov_b, 256, 128, 512, 8192, 512, 2048, 512, 65536, 128);

    // 7) out = ov_b @ Wo   (256 x 2048 x 2048), fp32 out
    gemm_mfma<true, false, false><<<dim3(32, 4), 256, 0, stream>>>(
        ov_b, Wo, out, 256, 2048, 2048, 2048, 2048, 2048, 0, 0, 0);
}